// Round 2
// baseline (1012.446 us; speedup 1.0000x reference)
//
#include <hip/hip_runtime.h>
#include <math.h>

// Problem constants: B=2, T=2048, C=1024, H=16, HD=64. All fp32.
// M = B*T = 4096 rows.

// ---------------- shared 128x128 fp32 GEMM core (K=1024, lda=ldw=1024) ----------------
// 256 threads, 8x8 micro-tile per thread, K-tile 16, LDS-staged.
__device__ __forceinline__ void sgemm_core(
    const float* __restrict__ A, const float* __restrict__ W,
    int m0, int n0, float (&acc)[8][8],
    float (&As)[16][132], float (&Bs)[16][128])
{
  const int tid = threadIdx.x;
  const int tx = tid & 15, ty = tid >> 4;
  const int ar = tid >> 2;          // 0..63  (A row within half-tile)
  const int ak = (tid & 3) << 2;    // 0,4,8,12 (k offset)
  const int bk = tid >> 5;          // 0..7   (B k-row)
  const int bn = (tid & 31) << 2;   // 0..124 (B col offset)

  for (int k0 = 0; k0 < 1024; k0 += 16) {
    const float4 a0 = *(const float4*)&A[(size_t)(m0 + ar) * 1024 + k0 + ak];
    const float4 a1 = *(const float4*)&A[(size_t)(m0 + 64 + ar) * 1024 + k0 + ak];
    const float4 b0 = *(const float4*)&W[(size_t)(k0 + bk) * 1024 + n0 + bn];
    const float4 b1 = *(const float4*)&W[(size_t)(k0 + 8 + bk) * 1024 + n0 + bn];
    __syncthreads();  // previous iteration's compute done with LDS
    // A stored transposed: As[k][row]; 2-way bank aliasing only (free).
    As[ak+0][ar] = a0.x; As[ak+1][ar] = a0.y; As[ak+2][ar] = a0.z; As[ak+3][ar] = a0.w;
    As[ak+0][64+ar] = a1.x; As[ak+1][64+ar] = a1.y; As[ak+2][64+ar] = a1.z; As[ak+3][64+ar] = a1.w;
    *(float4*)&Bs[bk][bn] = b0;
    *(float4*)&Bs[bk+8][bn] = b1;
    __syncthreads();
#pragma unroll
    for (int kk = 0; kk < 16; ++kk) {
      const float4 av0 = *(const float4*)&As[kk][ty*8];
      const float4 av1 = *(const float4*)&As[kk][ty*8+4];
      const float4 bv0 = *(const float4*)&Bs[kk][tx*8];
      const float4 bv1 = *(const float4*)&Bs[kk][tx*8+4];
      const float a[8] = {av0.x,av0.y,av0.z,av0.w,av1.x,av1.y,av1.z,av1.w};
      const float b[8] = {bv0.x,bv0.y,bv0.z,bv0.w,bv1.x,bv1.y,bv1.z,bv1.w};
#pragma unroll
      for (int i = 0; i < 8; ++i)
#pragma unroll
        for (int j = 0; j < 8; ++j)
          acc[i][j] = fmaf(a[i], b[j], acc[i][j]);
    }
  }
}

// ---------------- fused QKV projection ----------------
// Virtual GEMM: [4096,1024] @ [1024,3072]. Column block (128 wide) selects W in {Wq,Wk,Wv}.
// Output written directly in [B,H,T,HD] layout (+bias).
__global__ __launch_bounds__(256) void qkv_kernel(
    const float* __restrict__ x,
    const float* __restrict__ Wq, const float* __restrict__ bq,
    const float* __restrict__ Wk, const float* __restrict__ bk,
    const float* __restrict__ Wv, const float* __restrict__ bv,
    float* __restrict__ Q, float* __restrict__ K, float* __restrict__ V)
{
  __shared__ float As[16][132];
  __shared__ float Bs[16][128];

  const int gc0 = blockIdx.x * 128;       // 0..2944 (virtual col base)
  const int m0  = blockIdx.y * 128;
  const int w   = gc0 >> 10;              // 0=Q 1=K 2=V (128 | 1024)
  const int n0  = gc0 & 1023;
  const float* W    = (w == 0) ? Wq : (w == 1) ? Wk : Wv;
  const float* bias = (w == 0) ? bq : (w == 1) ? bk : bv;
  float* Out        = (w == 0) ? Q  : (w == 1) ? K  : V;

  float acc[8][8] = {};
  sgemm_core(x, W, m0, n0, acc, As, Bs);

  const int tid = threadIdx.x;
  const int tx = tid & 15, ty = tid >> 4;
  const int lc0 = tx * 8;                  // col offset within 128-tile
  const int h   = (n0 + lc0) >> 6;         // head (constant per thread: lc0%64 <= 56)
  const int hd0 = (n0 + lc0) & 63;
  const float4 bi0 = *(const float4*)&bias[n0 + lc0];
  const float4 bi1 = *(const float4*)&bias[n0 + lc0 + 4];
#pragma unroll
  for (int i = 0; i < 8; ++i) {
    const int m = m0 + ty * 8 + i;         // global row = b*T + t
    const int b = m >> 11, t = m & 2047;
    float* dst = &Out[(((size_t)(b * 16 + h)) * 2048 + t) * 64 + hd0];
    float4 r0 = make_float4(acc[i][0]+bi0.x, acc[i][1]+bi0.y, acc[i][2]+bi0.z, acc[i][3]+bi0.w);
    float4 r1 = make_float4(acc[i][4]+bi1.x, acc[i][5]+bi1.y, acc[i][6]+bi1.z, acc[i][7]+bi1.w);
    *(float4*)&dst[0] = r0;
    *(float4*)&dst[4] = r1;
  }
}

// ---------------- flash attention (causal), fp32 ----------------
// Grid: (T/64=32, B*H=32). Block: 256 threads, 4x4 micro over a 64x64 S tile.
// Q/K staged transposed [d][row]; V time-shares the K buffer (natural [k][d]); P in LDS.
__global__ __launch_bounds__(256) void attn_kernel(
    const float* __restrict__ Qg, const float* __restrict__ Kg,
    const float* __restrict__ Vg, float* __restrict__ AO)
{
  __shared__ float Qs[64][68];
  __shared__ float KVs[64][68];
  __shared__ float Ps[64][68];

  const int qt = blockIdx.x;
  const int bh = blockIdx.y;               // = b*H + h
  const int b  = bh >> 4;
  const int h  = bh & 15;
  const int q0 = qt * 64;
  const size_t base = (size_t)bh * (2048 * 64);

  const int tid  = threadIdx.x;
  const int tx   = tid & 15, ty = tid >> 4;
  const int lrow = tid >> 2;               // 0..63
  const int lof4 = (tid & 3) << 2;         // 0,4,8,12

  // Load Q tile transposed: Qs[d][row]
#pragma unroll
  for (int p = 0; p < 4; ++p) {
    const int d0 = p * 16 + lof4;
    const float4 q4 = *(const float4*)&Qg[base + (size_t)(q0 + lrow) * 64 + d0];
    Qs[d0+0][lrow] = q4.x; Qs[d0+1][lrow] = q4.y;
    Qs[d0+2][lrow] = q4.z; Qs[d0+3][lrow] = q4.w;
  }

  float m_run[4], l_run[4], o_acc[4][4];
#pragma unroll
  for (int i = 0; i < 4; ++i) {
    m_run[i] = -INFINITY; l_run[i] = 0.f;
#pragma unroll
    for (int j = 0; j < 4; ++j) o_acc[i][j] = 0.f;
  }

  for (int k0 = 0; k0 <= q0; k0 += 64) {
    // Prefetch K and V tiles into registers (hide V latency under S/softmax).
    float4 kreg[4], vreg[4];
#pragma unroll
    for (int p = 0; p < 4; ++p) {
      const int d0 = p * 16 + lof4;
      kreg[p] = *(const float4*)&Kg[base + (size_t)(k0 + lrow) * 64 + d0];
      vreg[p] = *(const float4*)&Vg[base + (size_t)(k0 + lrow) * 64 + d0];
    }
    __syncthreads();                        // (A) prev PV done with KVs/Ps
#pragma unroll
    for (int p = 0; p < 4; ++p) {           // K transposed: KVs[d][row]
      const int d0 = p * 16 + lof4;
      KVs[d0+0][lrow] = kreg[p].x; KVs[d0+1][lrow] = kreg[p].y;
      KVs[d0+2][lrow] = kreg[p].z; KVs[d0+3][lrow] = kreg[p].w;
    }
    __syncthreads();                        // (B) K (and first-iter Q) visible

    // S = Q K^T  (contract over d)
    float s[4][4] = {};
#pragma unroll 4
    for (int d = 0; d < 64; ++d) {
      const float4 qv = *(const float4*)&Qs[d][ty*4];
      const float4 kv = *(const float4*)&KVs[d][tx*4];
      const float qa[4] = {qv.x,qv.y,qv.z,qv.w};
      const float ka[4] = {kv.x,kv.y,kv.z,kv.w};
#pragma unroll
      for (int i = 0; i < 4; ++i)
#pragma unroll
        for (int j = 0; j < 4; ++j)
          s[i][j] = fmaf(qa[i], ka[j], s[i][j]);
    }

    // Online softmax (row state replicated across the 16 lanes of each row group)
    float4 p_st[4];
#pragma unroll
    for (int i = 0; i < 4; ++i) {
      const int qrow = q0 + ty * 4 + i;
      float sv[4];
#pragma unroll
      for (int j = 0; j < 4; ++j) {
        const int kcol = k0 + tx * 4 + j;
        const float v = s[i][j] * 0.125f;   // 1/sqrt(64)
        sv[j] = (kcol <= qrow) ? v : -INFINITY;
      }
      float mx = fmaxf(fmaxf(sv[0], sv[1]), fmaxf(sv[2], sv[3]));
#pragma unroll
      for (int o = 1; o < 16; o <<= 1) mx = fmaxf(mx, __shfl_xor(mx, o));
      const float m_new = fmaxf(m_run[i], mx);
      float ps = 0.f;
#pragma unroll
      for (int j = 0; j < 4; ++j) { sv[j] = __expf(sv[j] - m_new); ps += sv[j]; }
#pragma unroll
      for (int o = 1; o < 16; o <<= 1) ps += __shfl_xor(ps, o);
      const float alpha = __expf(m_run[i] - m_new);  // first iter: exp(-inf)=0
      l_run[i] = l_run[i] * alpha + ps;
      m_run[i] = m_new;
#pragma unroll
      for (int j = 0; j < 4; ++j) o_acc[i][j] *= alpha;
      p_st[i] = make_float4(sv[0], sv[1], sv[2], sv[3]);
    }
    __syncthreads();                        // (C) all S reads of KVs done

    // Stage P and V
#pragma unroll
    for (int i = 0; i < 4; ++i)
      *(float4*)&Ps[ty*4 + i][tx*4] = p_st[i];
#pragma unroll
    for (int p = 0; p < 4; ++p) {           // V natural: KVs[k][d]
      const int d0 = p * 16 + lof4;
      *(float4*)&KVs[lrow][d0] = vreg[p];
    }
    __syncthreads();                        // (D) P & V visible

    // O += P @ V  (contract over k)
#pragma unroll 4
    for (int k = 0; k < 64; ++k) {
      const float4 vv = *(const float4*)&KVs[k][tx*4];
      const float va[4] = {vv.x, vv.y, vv.z, vv.w};
      const float pr[4] = {Ps[ty*4+0][k], Ps[ty*4+1][k], Ps[ty*4+2][k], Ps[ty*4+3][k]};
#pragma unroll
      for (int i = 0; i < 4; ++i)
#pragma unroll
        for (int j = 0; j < 4; ++j)
          o_acc[i][j] = fmaf(pr[i], va[j], o_acc[i][j]);
    }
  }

  // Normalize and write to [B,T,C] with col = h*64 + d
#pragma unroll
  for (int i = 0; i < 4; ++i) {
    const float inv = 1.f / l_run[i];
    const int t = q0 + ty * 4 + i;
    float4 o4 = make_float4(o_acc[i][0]*inv, o_acc[i][1]*inv,
                            o_acc[i][2]*inv, o_acc[i][3]*inv);
    *(float4*)&AO[((size_t)(b * 2048 + t)) * 1024 + h * 64 + tx * 4] = o4;
  }
}

// ---------------- output projection ----------------
__global__ __launch_bounds__(256) void proj_kernel(
    const float* __restrict__ A, const float* __restrict__ W,
    const float* __restrict__ bias, float* __restrict__ Out)
{
  __shared__ float As[16][132];
  __shared__ float Bs[16][128];

  const int n0 = blockIdx.x * 128;
  const int m0 = blockIdx.y * 128;

  float acc[8][8] = {};
  sgemm_core(A, W, m0, n0, acc, As, Bs);

  const int tid = threadIdx.x;
  const int tx = tid & 15, ty = tid >> 4;
  const int lc0 = tx * 8;
  const float4 bi0 = *(const float4*)&bias[n0 + lc0];
  const float4 bi1 = *(const float4*)&bias[n0 + lc0 + 4];
#pragma unroll
  for (int i = 0; i < 8; ++i) {
    const int m = m0 + ty * 8 + i;
    float* dst = &Out[(size_t)m * 1024 + n0 + lc0];
    float4 r0 = make_float4(acc[i][0]+bi0.x, acc[i][1]+bi0.y, acc[i][2]+bi0.z, acc[i][3]+bi0.w);
    float4 r1 = make_float4(acc[i][4]+bi1.x, acc[i][5]+bi1.y, acc[i][6]+bi1.z, acc[i][7]+bi1.w);
    *(float4*)&dst[0] = r0;
    *(float4*)&dst[4] = r1;
  }
}

extern "C" void kernel_launch(void* const* d_in, const int* in_sizes, int n_in,
                              void* d_out, int out_size, void* d_ws, size_t ws_size,
                              hipStream_t stream) {
  const float* x  = (const float*)d_in[0];
  const float* Wq = (const float*)d_in[1];
  const float* bq = (const float*)d_in[2];
  const float* Wk = (const float*)d_in[3];
  const float* bk = (const float*)d_in[4];
  const float* Wv = (const float*)d_in[5];
  const float* bv = (const float*)d_in[6];
  const float* Wo = (const float*)d_in[7];
  const float* bo = (const float*)d_in[8];
  float* out = (float*)d_out;

  // Workspace: Q,K,V in [B,H,T,HD] + attention output in [B,T,C]. 4 x 16 MB = 64 MB.
  const size_t elems = (size_t)4096 * 1024;
  float* Q  = (float*)d_ws;
  float* K  = Q + elems;
  float* V  = K + elems;
  float* AO = V + elems;

  qkv_kernel<<<dim3(24, 32), 256, 0, stream>>>(x, Wq, bq, Wk, bk, Wv, bv, Q, K, V);
  attn_kernel<<<dim3(32, 32), 256, 0, stream>>>(Q, K, V, AO);
  proj_kernel<<<dim3(8, 32), 256, 0, stream>>>(AO, Wo, bo, out);
}

// Round 4
// 400.967 us; speedup vs baseline: 2.5250x; 2.5250x over previous
//
#include <hip/hip_runtime.h>
#include <hip/hip_bf16.h>
#include <math.h>

// B=2, T=2048, C=1024, H=16, HD=64. M = B*T = 4096 rows.
// Split-bf16 (Ootomo) MFMA everywhere: each fp32 product = ah*bh + ah*bl + al*bh
// (3 MFMAs, fp32 accumulate; dropped ll term ~2^-18 rel).
// Workspace layout (64 MB exactly — the size proven safe in round 2):
//   [ 0, 8)MB  Qh  (bf16 hi, pre-scaled by 1/8)   } aliased by AOh/AOl after attn
//   [ 8,16)MB  Ql  (lo)                           } (safe: per-(b,h,qtile) ownership)
//   [16,24)MB  Kh   [24,32)MB Kl     -- [b,t, h*64+d] rows
//   [32,40)MB  Vth  [40,48)MB Vtl    -- [b,h,d,t] (transposed for PV B-operand)
//   [48,64)MB  wqh,wql,wkh,wkl,wvh,wvl,woh,wol (2MB each, W^T [N][K] bf16)

typedef __attribute__((ext_vector_type(8))) short short8;  // 8 bf16 = 4 VGPR
typedef __attribute__((ext_vector_type(4))) float f32x4;   // mfma acc
union U8 { short8 s8; unsigned u[4]; };

#define MFMA16(A, B, C) __builtin_amdgcn_mfma_f32_16x16x32_bf16(A, B, C, 0, 0, 0)

// XOR swizzles — involutions, applied on BOTH source-address and read side (rule #21)
#define SW4(s, r) (((s) ^ (r) ^ ((r) >> 2)) & 3)  // 4 units per row
#define SW8(s, r) (((s) ^ (r)) & 7)               // 8 slots per row

static __device__ __forceinline__ unsigned pk2(float f0, float f1) {
  union { __hip_bfloat162 b; unsigned u; } c;
  c.b = __float22bfloat162_rn(make_float2(f0, f1));  // f0 -> low 16, f1 -> high 16
  return c.u;
}
// split pair: uh = [bf16(f0)|bf16(f1)], ul = residuals (also packed)
static __device__ __forceinline__ void splitpk(float f0, float f1,
                                               unsigned& uh, unsigned& ul) {
  unsigned h = pk2(f0, f1);
  float r0 = f0 - __uint_as_float(h << 16);
  float r1 = f1 - __uint_as_float(h & 0xffff0000u);
  uh = h;
  ul = pk2(r0, r1);
}
static __device__ __forceinline__ void gl_lds16(const void* g, void* l) {
  __builtin_amdgcn_global_load_lds(
      (const __attribute__((address_space(1))) void*)g,
      (__attribute__((address_space(3))) void*)l, 16, 0, 0);
}

// ---------------- prep: W [K][N] fp32 -> W^T hi/lo bf16 [N][K] ----------------
__global__ __launch_bounds__(256) void wprep(
    const float* __restrict__ Wq, const float* __restrict__ Wk,
    const float* __restrict__ Wv, const float* __restrict__ Wo,
    ushort* qh, ushort* ql, ushort* kh, ushort* kl,
    ushort* vh, ushort* vl, ushort* oh, ushort* ol)
{
  __shared__ float T[64][65];
  const int z = blockIdx.z;
  const float* W = (z == 0) ? Wq : (z == 1) ? Wk : (z == 2) ? Wv : Wo;
  ushort* H = (z == 0) ? qh : (z == 1) ? kh : (z == 2) ? vh : oh;
  ushort* L = (z == 0) ? ql : (z == 1) ? kl : (z == 2) ? vl : ol;
  const int k0 = blockIdx.x * 64, n0 = blockIdx.y * 64;
  const int tid = threadIdx.x;
  const int rr = tid >> 4, c4 = (tid & 15) * 4;
#pragma unroll
  for (int p = 0; p < 4; ++p) {
    float4 v = *(const float4*)&W[(size_t)(k0 + p * 16 + rr) * 1024 + n0 + c4];
    T[p * 16 + rr][c4 + 0] = v.x; T[p * 16 + rr][c4 + 1] = v.y;
    T[p * 16 + rr][c4 + 2] = v.z; T[p * 16 + rr][c4 + 3] = v.w;
  }
  __syncthreads();
#pragma unroll
  for (int p = 0; p < 4; ++p) {
    int nr = p * 16 + rr;
    unsigned uh01, ul01, uh23, ul23;
    splitpk(T[c4 + 0][nr], T[c4 + 1][nr], uh01, ul01);
    splitpk(T[c4 + 2][nr], T[c4 + 3][nr], uh23, ul23);
    size_t a = (size_t)(n0 + nr) * 1024 + k0 + c4;   // 8B-aligned (c4 % 4 == 0)
    *(uint2*)&H[a] = make_uint2(uh01, uh23);
    *(uint2*)&L[a] = make_uint2(ul01, ul23);
  }
}

// ---------------- 128x128 MFMA GEMM core (K=1024), 4 waves 2x2, BK=32 ----------
// AFP32=true : A0 = fp32 A [M][1024], split on the fly (qkv: A = x)
// AFP32=false: A0/A1 = bf16 hi/lo A [M][1024] (proj: A = AO)
// B always: Bh/Bl = bf16 hi/lo W^T [N][1024].
template <bool AFP32>
__device__ __forceinline__ void gemm_core(
    const void* A0, const void* A1,
    const ushort* __restrict__ Bh, const ushort* __restrict__ Bl,
    int m0, int n0, f32x4 (&acc)[4][4])
{
  __shared__ __align__(16) char SM[32768];
  const int tid = threadIdx.x, lane = tid & 63, w = tid >> 6;
  const int wm = w >> 1, wn = w & 1;
  const int r16 = lane & 15, kg = lane >> 4;

  for (int k0 = 0; k0 < 1024; k0 += 32) {
    __syncthreads();  // prev iteration's LDS reads done
    if constexpr (AFP32) {
      if (w < 2) {  // waves 0,1: A fp32 [128][32] -> SM[0,16384), 128B rows
        const float* A = (const float*)A0;
        const int lr8 = lane >> 3, ls = lane & 7;
        const int u = ls >> 1, hf = (ls & 1) * 4;  // 32B unit + 16B half
#pragma unroll
        for (int c = 0; c < 8; ++c) {
          const int row = w * 64 + c * 8 + lr8;
          const float* g = A + (size_t)(m0 + row) * 1024 + k0 + SW4(u, row) * 8 + hf;
          gl_lds16(g, SM + w * 8192 + c * 1024);
        }
      } else {      // waves 2,3: Bh/Bl ushort [128][32] -> SM[16384,32768), 64B rows
        const ushort* src = (w == 2) ? Bh : Bl;
        const int lr = lane >> 2, ls = lane & 3;
#pragma unroll
        for (int c = 0; c < 8; ++c) {
          const int row = c * 16 + lr;
          const ushort* g = src + (size_t)(n0 + row) * 1024 + k0 + SW4(ls, row) * 8;
          gl_lds16(g, SM + 16384 + (w - 2) * 8192 + c * 1024);
        }
      }
    } else {        // 4 buffers Ah/Al/Bh/Bl, one per wave, 64B rows
      const ushort* src = (w == 0) ? (const ushort*)A0
                        : (w == 1) ? (const ushort*)A1
                        : (w == 2) ? Bh : Bl;
      const int rbase = (w < 2) ? m0 : n0;
      const int lr = lane >> 2, ls = lane & 3;
#pragma unroll
      for (int c = 0; c < 8; ++c) {
        const int row = c * 16 + lr;
        const ushort* g = src + (size_t)(rbase + row) * 1024 + k0 + SW4(ls, row) * 8;
        gl_lds16(g, SM + w * 8192 + c * 1024);
      }
    }
    __syncthreads();  // staging visible (vmcnt drained by barrier)

    short8 ah[4], al[4], bh[4], bl[4];
    if constexpr (AFP32) {
      const float* SA = (const float*)SM;
#pragma unroll
      for (int f = 0; f < 4; ++f) {
        const int ra = wm * 64 + f * 16 + r16;
        const int ad = ra * 32 + SW4(kg, ra) * 8;
        f32x4 x0 = *(const f32x4*)&SA[ad];
        f32x4 x1 = *(const f32x4*)&SA[ad + 4];
        U8 H, L;
        splitpk(x0[0], x0[1], H.u[0], L.u[0]);
        splitpk(x0[2], x0[3], H.u[1], L.u[1]);
        splitpk(x1[0], x1[1], H.u[2], L.u[2]);
        splitpk(x1[2], x1[3], H.u[3], L.u[3]);
        ah[f] = H.s8; al[f] = L.s8;
      }
      const ushort* SBh = (const ushort*)(SM + 16384);
      const ushort* SBl = (const ushort*)(SM + 24576);
#pragma unroll
      for (int f = 0; f < 4; ++f) {
        const int rb = wn * 64 + f * 16 + r16;
        const int ab = rb * 32 + SW4(kg, rb) * 8;
        bh[f] = *(const short8*)&SBh[ab];
        bl[f] = *(const short8*)&SBl[ab];
      }
    } else {
      const ushort* SAh = (const ushort*)SM;
      const ushort* SAl = (const ushort*)(SM + 8192);
      const ushort* SBh = (const ushort*)(SM + 16384);
      const ushort* SBl = (const ushort*)(SM + 24576);
#pragma unroll
      for (int f = 0; f < 4; ++f) {
        const int ra = wm * 64 + f * 16 + r16;
        const int aa = ra * 32 + SW4(kg, ra) * 8;
        ah[f] = *(const short8*)&SAh[aa];
        al[f] = *(const short8*)&SAl[aa];
        const int rb = wn * 64 + f * 16 + r16;
        const int ab = rb * 32 + SW4(kg, rb) * 8;
        bh[f] = *(const short8*)&SBh[ab];
        bl[f] = *(const short8*)&SBl[ab];
      }
    }
#pragma unroll
    for (int i = 0; i < 4; ++i)
#pragma unroll
      for (int j = 0; j < 4; ++j) {
        acc[i][j] = MFMA16(ah[i], bh[j], acc[i][j]);
        acc[i][j] = MFMA16(ah[i], bl[j], acc[i][j]);
        acc[i][j] = MFMA16(al[i], bh[j], acc[i][j]);
      }
  }
}

// ---------------- QKV projection: x @ {Wq,Wk,Wv} + bias -> split outputs -------
__global__ __launch_bounds__(256) void qkv_gemm(
    const float* __restrict__ x,
    const ushort* __restrict__ wqh, const ushort* __restrict__ wql,
    const ushort* __restrict__ wkh, const ushort* __restrict__ wkl,
    const ushort* __restrict__ wvh, const ushort* __restrict__ wvl,
    const float* __restrict__ bq, const float* __restrict__ bk,
    const float* __restrict__ bv,
    ushort* __restrict__ Qh, ushort* __restrict__ Ql,
    ushort* __restrict__ Kh, ushort* __restrict__ Kl,
    ushort* __restrict__ Vth, ushort* __restrict__ Vtl)
{
  const int ts = blockIdx.x >> 3;            // 0=Q 1=K 2=V
  const int n0 = (blockIdx.x & 7) * 128;
  const int m0 = blockIdx.y * 128;
  const ushort* Bh = (ts == 0) ? wqh : (ts == 1) ? wkh : wvh;
  const ushort* Bl = (ts == 0) ? wql : (ts == 1) ? wkl : wvl;
  const float* bias = (ts == 0) ? bq : (ts == 1) ? bk : bv;

  f32x4 zv = {0.f, 0.f, 0.f, 0.f};
  f32x4 acc[4][4];
#pragma unroll
  for (int i = 0; i < 4; ++i)
#pragma unroll
    for (int j = 0; j < 4; ++j) acc[i][j] = zv;

  gemm_core<true>(x, nullptr, Bh, Bl, m0, n0, acc);

  const int lane = threadIdx.x & 63, w = threadIdx.x >> 6;
  const int wm = w >> 1, wn = w & 1, r16 = lane & 15, g4 = (lane >> 4) * 4;
  const float scale = (ts == 0) ? 0.125f : 1.0f;   // fold 1/sqrt(64) into Q
  ushort* H = (ts == 0) ? Qh : Kh;
  ushort* L = (ts == 0) ? Ql : Kl;
#pragma unroll
  for (int j = 0; j < 4; ++j) {
    const int nc = n0 + wn * 64 + j * 16 + r16;
    const float bb = bias[nc];
#pragma unroll
    for (int i = 0; i < 4; ++i) {
      const int mr = m0 + wm * 64 + i * 16 + g4;   // rows mr..mr+3 (same b: mr%4==0)
      float v0 = (acc[i][j][0] + bb) * scale;
      float v1 = (acc[i][j][1] + bb) * scale;
      float v2 = (acc[i][j][2] + bb) * scale;
      float v3 = (acc[i][j][3] + bb) * scale;
      unsigned uh01, ul01, uh23, ul23;
      splitpk(v0, v1, uh01, ul01);
      splitpk(v2, v3, uh23, ul23);
      if (ts < 2) {      // Q/K: [b,t, h*64+d] rows, scalar stores down 4 rows
        size_t a0 = (size_t)mr * 1024 + nc;
        H[a0]        = (ushort)(uh01 & 0xffffu);
        H[a0 + 1024] = (ushort)(uh01 >> 16);
        H[a0 + 2048] = (ushort)(uh23 & 0xffffu);
        H[a0 + 3072] = (ushort)(uh23 >> 16);
        L[a0]        = (ushort)(ul01 & 0xffffu);
        L[a0 + 1024] = (ushort)(ul01 >> 16);
        L[a0 + 2048] = (ushort)(ul23 & 0xffffu);
        L[a0 + 3072] = (ushort)(ul23 >> 16);
      } else {           // V: transposed scatter [b,h,d,t]; 4 consecutive t = 2 dwords
        const int b = mr >> 11, t0 = mr & 2047;
        const int hh = nc >> 6, d = nc & 63;
        size_t a0 = ((size_t)((b * 16 + hh) * 64 + d)) * 2048 + t0;  // t0%4==0 -> aligned
        *(unsigned*)&Vth[a0]     = uh01;
        *(unsigned*)&Vth[a0 + 2] = uh23;
        *(unsigned*)&Vtl[a0]     = ul01;
        *(unsigned*)&Vtl[a0 + 2] = ul23;
      }
    }
  }
}

// ---------------- flash attention (causal), split-bf16 MFMA --------------------
// 256 thr = 4 waves x 32 q-rows (QBLK=128), KV tile 64. 2 barriers per tile.
__global__ __launch_bounds__(256) void attn(
    const ushort* __restrict__ Qh, const ushort* __restrict__ Ql,
    const ushort* __restrict__ Kgh, const ushort* __restrict__ Kgl,
    const ushort* __restrict__ Vth, const ushort* __restrict__ Vtl,
    ushort* __restrict__ AOh, ushort* __restrict__ AOl)
{
  __shared__ __align__(16) ushort KhL[64 * 64], KlL[64 * 64];
  __shared__ __align__(16) ushort VhL[64 * 64], VlL[64 * 64];
  __shared__ __align__(16) ushort Ph[4][32 * 64], Pl[4][32 * 64];

  const int id = blockIdx.x;
  const int bh = id & 31;
  const int qr = id >> 5;
  const int qt = (qr < 8) ? qr : 23 - qr;    // pair (q, 15-q) for causal balance
  const int b = bh >> 4, h = bh & 15;
  const int q0 = qt * 128;

  const int tid = threadIdx.x, lane = tid & 63, w = tid >> 6;
  const int r16 = lane & 15, lg = lane >> 4;

  // Q fragments direct from global (pre-scaled, pre-split). A-frag: row=lane&15,
  // k = d = (lane>>4)*8 + j (+32*s half).
  short8 qh[2][2], ql[2][2];
#pragma unroll
  for (int mf = 0; mf < 2; ++mf)
#pragma unroll
    for (int s = 0; s < 2; ++s) {
      const int q = q0 + w * 32 + mf * 16 + r16;
      size_t a = (size_t)(b * 2048 + q) * 1024 + h * 64 + 32 * s + lg * 8;
      qh[mf][s] = *(const short8*)&Qh[a];
      ql[mf][s] = *(const short8*)&Ql[a];
    }

  f32x4 zv = {0.f, 0.f, 0.f, 0.f};
  f32x4 o[2][4];
  float m_run[2][4], l_run[2][4];
#pragma unroll
  for (int mf = 0; mf < 2; ++mf) {
#pragma unroll
    for (int nf = 0; nf < 4; ++nf) o[mf][nf] = zv;
#pragma unroll
    for (int r = 0; r < 4; ++r) { m_run[mf][r] = -INFINITY; l_run[mf][r] = 0.f; }
  }

  ushort* php = &Ph[w][0];
  ushort* plp = &Pl[w][0];

  for (int k0 = 0; k0 < q0 + 128; k0 += 64) {
    __syncthreads();  // (A) prev S/PV reads of K/V LDS done
    // V hi/lo via global_load_lds: LDS [d][64t] linear, source t-slot swizzled
#pragma unroll
    for (int i = 0; i < 4; ++i) {
      const int qc = w * 4 + i;          // 0..15: 0-7 -> hi, 8-15 -> lo
      const int cc = qc & 7;
      const int d = cc * 8 + (lane >> 3);
      const ushort* srcv = ((qc >> 3) ? Vtl : Vth) +
                           (size_t)(bh * 64 + d) * 2048 + k0 + SW8(lane & 7, d) * 8;
      gl_lds16(srcv, (char*)((qc >> 3) ? VlL : VhL) + cc * 1024);
    }
    // K tile: coalesced loads + swizzled ds_write, LDS [t][64d]
#pragma unroll
    for (int p = 0; p < 4; ++p) {
      const int tr = p * 16 + (tid >> 4);
      const int d0 = (tid & 15) * 4;
      size_t ga = (size_t)(b * 2048 + k0 + tr) * 1024 + h * 64 + d0;
      ushort4 h4 = *(const ushort4*)&Kgh[ga];
      ushort4 l4 = *(const ushort4*)&Kgl[ga];
      const int ad = tr * 64 + SW8(d0 >> 3, tr) * 8 + (tid & 1) * 4;
      *(ushort4*)&KhL[ad] = h4;
      *(ushort4*)&KlL[ad] = l4;
    }
    __syncthreads();  // (B) staging visible

    // S = Q K^T (pre-scaled). B-frag: col=kv=lane&15, k=d
    f32x4 sf[2][4];
#pragma unroll
    for (int mf = 0; mf < 2; ++mf)
#pragma unroll
      for (int nf = 0; nf < 4; ++nf) sf[mf][nf] = zv;
#pragma unroll
    for (int s = 0; s < 2; ++s) {
      short8 kh_[4], kl_[4];
#pragma unroll
      for (int nf = 0; nf < 4; ++nf) {
        const int kv = nf * 16 + r16;
        const int ad = kv * 64 + SW8(4 * s + lg, kv) * 8;
        kh_[nf] = *(const short8*)&KhL[ad];
        kl_[nf] = *(const short8*)&KlL[ad];
      }
#pragma unroll
      for (int mf = 0; mf < 2; ++mf)
#pragma unroll
        for (int nf = 0; nf < 4; ++nf) {
          sf[mf][nf] = MFMA16(qh[mf][s], kh_[nf], sf[mf][nf]);
          sf[mf][nf] = MFMA16(qh[mf][s], kl_[nf], sf[mf][nf]);
          sf[mf][nf] = MFMA16(ql[mf][s], kh_[nf], sf[mf][nf]);
        }
    }

    // causal mask + online softmax; C/D: row=(lane>>4)*4+r, col=lane&15 (+16*nf)
#pragma unroll
    for (int mf = 0; mf < 2; ++mf) {
#pragma unroll
      for (int r = 0; r < 4; ++r) {
        const int qg = q0 + w * 32 + mf * 16 + lg * 4 + r;
#pragma unroll
        for (int nf = 0; nf < 4; ++nf) {
          const int kvg = k0 + nf * 16 + r16;
          if (kvg > qg) sf[mf][nf][r] = -INFINITY;
        }
        float mx = fmaxf(fmaxf(sf[mf][0][r], sf[mf][1][r]),
                         fmaxf(sf[mf][2][r], sf[mf][3][r]));
        mx = fmaxf(mx, __shfl_xor(mx, 1));
        mx = fmaxf(mx, __shfl_xor(mx, 2));
        mx = fmaxf(mx, __shfl_xor(mx, 4));
        mx = fmaxf(mx, __shfl_xor(mx, 8));
        const float mn = fmaxf(m_run[mf][r], mx);
        const float ms = fmaxf(mn, -1e30f);           // fully-masked-row safety
        const float al_ = __expf(m_run[mf][r] - ms);  // first iter: exp(-inf)=0
        float ps = 0.f;
#pragma unroll
        for (int nf = 0; nf < 4; ++nf) {
          const float p = __expf(sf[mf][nf][r] - ms);
          sf[mf][nf][r] = p;
          ps += p;
        }
        ps += __shfl_xor(ps, 1); ps += __shfl_xor(ps, 2);
        ps += __shfl_xor(ps, 4); ps += __shfl_xor(ps, 8);
        l_run[mf][r] = l_run[mf][r] * al_ + ps;
        m_run[mf][r] = mn;
#pragma unroll
        for (int nf = 0; nf < 4; ++nf) o[mf][nf][r] *= al_;
      }
      // stage P split (wave-private LDS, no barrier needed)
#pragma unroll
      for (int r = 0; r < 4; ++r) {
        const int row = mf * 16 + lg * 4 + r;
        unsigned uh01, ul01, uh23, ul23;
        splitpk(sf[mf][0][r], sf[mf][1][r], uh01, ul01);
        splitpk(sf[mf][2][r], sf[mf][3][r], uh23, ul23);
        const int p7 = r16 & 7;
        const int a0 = row * 64 + SW8((r16 >> 3) + 0, row) * 8 + p7;
        const int a1 = row * 64 + SW8((r16 >> 3) + 2, row) * 8 + p7;
        const int a2 = row * 64 + SW8((r16 >> 3) + 4, row) * 8 + p7;
        const int a3 = row * 64 + SW8((r16 >> 3) + 6, row) * 8 + p7;
        php[a0] = (ushort)(uh01 & 0xffffu);
        php[a1] = (ushort)(uh01 >> 16);
        php[a2] = (ushort)(uh23 & 0xffffu);
        php[a3] = (ushort)(uh23 >> 16);
        plp[a0] = (ushort)(ul01 & 0xffffu);
        plp[a1] = (ushort)(ul01 >> 16);
        plp[a2] = (ushort)(ul23 & 0xffffu);
        plp[a3] = (ushort)(ul23 >> 16);
      }
    }

    // O += P V : A-frag = P (row=q, k=t), B-frag = V (col=d, k=t)
#pragma unroll
    for (int s2 = 0; s2 < 2; ++s2) {
      short8 ph_[2], pl_[2], vh_[4], vl_[4];
#pragma unroll
      for (int mf = 0; mf < 2; ++mf) {
        const int row = mf * 16 + r16;
        const int ad = row * 64 + SW8(4 * s2 + lg, row) * 8;
        ph_[mf] = *(const short8*)&php[ad];
        pl_[mf] = *(const short8*)&plp[ad];
      }
#pragma unroll
      for (int nf = 0; nf < 4; ++nf) {
        const int d = nf * 16 + r16;
        const int ad = d * 64 + SW8(4 * s2 + lg, d) * 8;
        vh_[nf] = *(const short8*)&VhL[ad];
        vl_[nf] = *(const short8*)&VlL[ad];
      }
#pragma unroll
      for (int mf = 0; mf < 2; ++mf)
#pragma unroll
        for (int nf = 0; nf < 4; ++nf) {
          o[mf][nf] = MFMA16(ph_[mf], vh_[nf], o[mf][nf]);
          o[mf][nf] = MFMA16(ph_[mf], vl_[nf], o[mf][nf]);
          o[mf][nf] = MFMA16(pl_[mf], vh_[nf], o[mf][nf]);
        }
    }
  }

  // epilogue: normalize, split, write AO hi/lo (aliases Qh/Ql — safe, see header)
#pragma unroll
  for (int mf = 0; mf < 2; ++mf)
#pragma unroll
    for (int r = 0; r < 4; ++r) {
      const float inv = 1.f / l_run[mf][r];
      const int q = q0 + w * 32 + mf * 16 + lg * 4 + r;
      const size_t base = (size_t)(b * 2048 + q) * 1024 + h * 64;
      unsigned uh01, ul01, uh23, ul23;
      splitpk(o[mf][0][r] * inv, o[mf][1][r] * inv, uh01, ul01);
      splitpk(o[mf][2][r] * inv, o[mf][3][r] * inv, uh23, ul23);
      AOh[base + r16]      = (ushort)(uh01 & 0xffffu);
      AOh[base + 16 + r16] = (ushort)(uh01 >> 16);
      AOh[base + 32 + r16] = (ushort)(uh23 & 0xffffu);
      AOh[base + 48 + r16] = (ushort)(uh23 >> 16);
      AOl[base + r16]      = (ushort)(ul01 & 0xffffu);
      AOl[base + 16 + r16] = (ushort)(ul01 >> 16);
      AOl[base + 32 + r16] = (ushort)(ul23 & 0xffffu);
      AOl[base + 48 + r16] = (ushort)(ul23 >> 16);
    }
}

// ---------------- output projection: AO @ Wo + bo -> out (fp32) ----------------
__global__ __launch_bounds__(256) void proj_gemm(
    const ushort* __restrict__ aoh, const ushort* __restrict__ aol,
    const ushort* __restrict__ woh, const ushort* __restrict__ wol,
    const float* __restrict__ bo, float* __restrict__ out)
{
  const int n0 = blockIdx.x * 128, m0 = blockIdx.y * 128;
  f32x4 zv = {0.f, 0.f, 0.f, 0.f};
  f32x4 acc[4][4];
#pragma unroll
  for (int i = 0; i < 4; ++i)
#pragma unroll
    for (int j = 0; j < 4; ++j) acc[i][j] = zv;

  gemm_core<false>(aoh, aol, woh, wol, m0, n0, acc);

  const int lane = threadIdx.x & 63, w = threadIdx.x >> 6;
  const int wm = w >> 1, wn = w & 1, r16 = lane & 15, g4 = (lane >> 4) * 4;
#pragma unroll
  for (int j = 0; j < 4; ++j) {
    const int nc = n0 + wn * 64 + j * 16 + r16;
    const float bb = bo[nc];
#pragma unroll
    for (int i = 0; i < 4; ++i) {
      const int mr = m0 + wm * 64 + i * 16 + g4;
#pragma unroll
      for (int r = 0; r < 4; ++r)
        out[(size_t)(mr + r) * 1024 + nc] = acc[i][j][r] + bb;
    }
  }
}

extern "C" void kernel_launch(void* const* d_in, const int* in_sizes, int n_in,
                              void* d_out, int out_size, void* d_ws, size_t ws_size,
                              hipStream_t stream) {
  const float* x  = (const float*)d_in[0];
  const float* Wq = (const float*)d_in[1];
  const float* bq = (const float*)d_in[2];
  const float* Wk = (const float*)d_in[3];
  const float* bk = (const float*)d_in[4];
  const float* Wv = (const float*)d_in[5];
  const float* bv = (const float*)d_in[6];
  const float* Wo = (const float*)d_in[7];
  const float* bo = (const float*)d_in[8];
  float* out = (float*)d_out;
  (void)in_sizes; (void)n_in; (void)out_size; (void)ws_size;

  const size_t MB = 1u << 20;
  char* ws = (char*)d_ws;
  ushort* Qh  = (ushort*)(ws + 0 * MB);
  ushort* Ql  = (ushort*)(ws + 8 * MB);
  ushort* Kh  = (ushort*)(ws + 16 * MB);
  ushort* Kl  = (ushort*)(ws + 24 * MB);
  ushort* Vth = (ushort*)(ws + 32 * MB);
  ushort* Vtl = (ushort*)(ws + 40 * MB);
  ushort* wqh = (ushort*)(ws + 48 * MB);
  ushort* wql = (ushort*)(ws + 50 * MB);
  ushort* wkh = (ushort*)(ws + 52 * MB);
  ushort* wkl = (ushort*)(ws + 54 * MB);
  ushort* wvh = (ushort*)(ws + 56 * MB);
  ushort* wvl = (ushort*)(ws + 58 * MB);
  ushort* woh = (ushort*)(ws + 60 * MB);
  ushort* wol = (ushort*)(ws + 62 * MB);
  ushort* AOh = Qh;   // alias: attn writes exactly the Q region it owns
  ushort* AOl = Ql;

  wprep<<<dim3(16, 16, 4), 256, 0, stream>>>(Wq, Wk, Wv, Wo,
                                             wqh, wql, wkh, wkl, wvh, wvl, woh, wol);
  qkv_gemm<<<dim3(24, 32), 256, 0, stream>>>(x, wqh, wql, wkh, wkl, wvh, wvl,
                                             bq, bk, bv, Qh, Ql, Kh, Kl, Vth, Vtl);
  attn<<<dim3(512), 256, 0, stream>>>(Qh, Ql, Kh, Kl, Vth, Vtl, AOh, AOl);
  proj_gemm<<<dim3(8, 32), 256, 0, stream>>>(AOh, AOl, woh, wol, bo, out);
}